// Round 6
// baseline (255.655 us; speedup 1.0000x reference)
//
#include <hip/hip_runtime.h>
#include <math.h>

#define EMBED   2048
#define NEXP    64
#define BATCHN  16384
#define RT      32              // rows per block; each wave: 32 rows x 64 experts x K/4
#define NT_A    256
#define LCAP    16380           // flag-list capacity (fits in 64KB ws slot)
#define MARGIN_THRESH 4e-4f     // bf16-split logit err ~1e-5 abs; 40x margin

typedef float  f32x4  __attribute__((ext_vector_type(4)));
typedef __bf16 bf16x8 __attribute__((ext_vector_type(8)));

// split fp32 -> bf16 hi + bf16 lo (x ~= hi + lo, residual ~2^-18 |x|)
__device__ __forceinline__ void cvt8(const float4& a, const float4& b,
                                     bf16x8& h, bf16x8& l) {
    float f[8] = {a.x, a.y, a.z, a.w, b.x, b.y, b.z, b.w};
    #pragma unroll
    for (int j = 0; j < 8; ++j) {
        __bf16 hh = (__bf16)f[j];
        h[j] = hh;
        l[j] = (__bf16)(f[j] - (float)hh);   // x - hi exact in fp32
    }
}

// ---------------- Kernel 0: pack W -> hi/lo B-fragment layout, zero flag count ----
// Wt[tile][kcg][lane][8]: lane holds col=lane&15, k=kcg*32+(lane>>4)*8+j.
// Same (lane>>4, j) -> k map as the A fragments => K-consistent.
// (layout hardware-verified in rounds 3/5)
__global__ __launch_bounds__(256)
void pack_w_kernel(const float* __restrict__ W, __bf16* __restrict__ Wh,
                   __bf16* __restrict__ Wl, int* __restrict__ flagcnt)
{
    const int g = blockIdx.x * 256 + threadIdx.x;    // 16384 = 4 tiles * 64 kcg * 64 lanes
    if (g == 0) *flagcnt = 0;
    const int tile = g >> 12, rem = g & 4095;
    const int kc = rem >> 6, ln = rem & 63;
    const int e = tile * 16 + (ln & 15);
    const int k = kc * 32 + (ln >> 4) * 8;
    const float* wp = W + (size_t)e * EMBED + k;
    float4 a = *(const float4*)wp, b = *(const float4*)(wp + 4);
    bf16x8 h, l;
    cvt8(a, b, h, l);
    *(bf16x8*)(Wh + (size_t)g * 8) = h;              // coalesced 16B stores
    *(bf16x8*)(Wl + (size_t)g * 8) = l;
}

// ---------------- Kernel A: barrier-free register bf16-split MFMA GEMM + top-2 ----
// 512 blocks x 4 waves; wave ks covers rows [row0,row0+32) x 64 experts x K-slice
// [ks*512,(ks+1)*512). A-fragments loaded DIRECTLY from global x in fragment
// order (16 rows x 128B contiguous per kc) + in-register hi/lo split: no LDS
// staging, no K-loop barriers. Per kc per wave: 4 x-float4 (prefetched 1 kc
// ahead), 8 B-loads (L2-resident Wh/Wl), 24 MFMA. One LDS reduction at the end.
__global__ __launch_bounds__(NT_A, 2)
void gemm_topk_kernel(const float* __restrict__ x, const __bf16* __restrict__ Wh,
                      const __bf16* __restrict__ Wl, const float* __restrict__ bias,
                      float* __restrict__ out, int* __restrict__ flagcnt,
                      int* __restrict__ flaglist)
{
    __shared__ float shred[3][64][33];   // +1 pad: conflict-free scalar reduce, 25.3 KB
    __shared__ float lg[RT][64];         // 8 KB

    const int tid  = threadIdx.x;
    const int lane = tid & 63;
    const int ks   = tid >> 6;                     // wave = K slice
    const int row0 = blockIdx.x * RT;

    // A-fragment source: row = row0+(lane&15) (+16 for rh=1), k = ks*512 + kc*32 + (lane>>4)*8
    const float* xr0 = x + (size_t)(row0 + (lane & 15)) * EMBED + ks * 512 + ((lane >> 4) & 3) * 8;
    const float* xr1 = xr0 + (size_t)16 * EMBED;
    const __bf16* whb = Wh + ((size_t)(ks * 16) * 64 + lane) * 8;  // + t*32768 + kc*512
    const __bf16* wlb = Wl + ((size_t)(ks * 16) * 64 + lane) * 8;

    f32x4 acc[2][4] = {};                          // [rh][tile]

    float4 a0 = *(const float4*)(xr0), b0 = *(const float4*)(xr0 + 4);
    float4 a1 = *(const float4*)(xr1), b1 = *(const float4*)(xr1 + 4);

    #pragma unroll 1
    for (int kc = 0; kc < 16; ++kc) {
        float4 na0, nb0, na1, nb1;
        if (kc < 15) {                             // prefetch next kc's x (full HBM latency cover)
            na0 = *(const float4*)(xr0 + (kc + 1) * 32);
            nb0 = *(const float4*)(xr0 + (kc + 1) * 32 + 4);
            na1 = *(const float4*)(xr1 + (kc + 1) * 32);
            nb1 = *(const float4*)(xr1 + (kc + 1) * 32 + 4);
        }
        bf16x8 ah0, al0, ah1, al1;
        cvt8(a0, b0, ah0, al0);
        cvt8(a1, b1, ah1, al1);
        #pragma unroll
        for (int t = 0; t < 4; ++t) {
            bf16x8 bh = *(const bf16x8*)(whb + (size_t)t * 32768 + (size_t)kc * 512);
            bf16x8 bl = *(const bf16x8*)(wlb + (size_t)t * 32768 + (size_t)kc * 512);
            acc[0][t] = __builtin_amdgcn_mfma_f32_16x16x32_bf16(ah0, bh, acc[0][t], 0, 0, 0);
            acc[0][t] = __builtin_amdgcn_mfma_f32_16x16x32_bf16(ah0, bl, acc[0][t], 0, 0, 0);
            acc[0][t] = __builtin_amdgcn_mfma_f32_16x16x32_bf16(al0, bh, acc[0][t], 0, 0, 0);
            acc[1][t] = __builtin_amdgcn_mfma_f32_16x16x32_bf16(ah1, bh, acc[1][t], 0, 0, 0);
            acc[1][t] = __builtin_amdgcn_mfma_f32_16x16x32_bf16(ah1, bl, acc[1][t], 0, 0, 0);
            acc[1][t] = __builtin_amdgcn_mfma_f32_16x16x32_bf16(al1, bh, acc[1][t], 0, 0, 0);
        }
        a0 = na0; b0 = nb0; a1 = na1; b1 = nb1;
    }

    // cross-wave K reduction (once per block; padded rows -> conflict-free)
    if (ks > 0) {
        #pragma unroll
        for (int rh = 0; rh < 2; ++rh)
            #pragma unroll
            for (int t = 0; t < 4; ++t)
                #pragma unroll
                for (int q = 0; q < 4; ++q)
                    shred[ks - 1][lane][(rh * 4 + t) * 4 + q] = acc[rh][t][q];
    }
    __syncthreads();
    if (ks == 0) {
        #pragma unroll
        for (int w = 0; w < 3; ++w)
            #pragma unroll
            for (int rh = 0; rh < 2; ++rh)
                #pragma unroll
                for (int t = 0; t < 4; ++t)
                    #pragma unroll
                    for (int q = 0; q < 4; ++q)
                        acc[rh][t][q] += shred[w][lane][(rh * 4 + t) * 4 + q];
        // D layout (m89-verified): col = lane&15, row_local = (lane>>4)*4 + reg (+16 for rh=1)
        #pragma unroll
        for (int t = 0; t < 4; ++t) {
            const float bb = bias[t * 16 + (lane & 15)];
            #pragma unroll
            for (int q = 0; q < 4; ++q) {
                lg[((lane >> 4) & 3) * 4 + q][t * 16 + (lane & 15)]      = acc[0][t][q] + bb;
                lg[16 + ((lane >> 4) & 3) * 4 + q][t * 16 + (lane & 15)] = acc[1][t][q] + bb;
            }
        }
    }
    __syncthreads();

    // top-2 (+margin via top-3): wave ks handles rows 8ks..8ks+7, lane = expert
    #pragma unroll 1
    for (int r = 0; r < 8; ++r) {
        const int row_l = ks * 8 + r;
        float v1 = lg[row_l][lane], v2 = -INFINITY, v3 = -INFINITY;
        int   i1 = lane, i2 = 0;
        #pragma unroll
        for (int m = 1; m <= 32; m <<= 1) {
            const float o1  = __shfl_xor(v1, m, 64);
            const int   oi1 = __shfl_xor(i1, m, 64);
            const float o2  = __shfl_xor(v2, m, 64);
            const int   oi2 = __shfl_xor(i2, m, 64);
            const float o3  = __shfl_xor(v3, m, 64);
            if (o1 > v1) {
                float nv2; int ni2; float nv3;
                if (v1 > o2) { nv2 = v1; ni2 = i1;  nv3 = fmaxf(v2, o2); }
                else         { nv2 = o2; ni2 = oi2; nv3 = fmaxf(v1, o3); }
                v1 = o1; i1 = oi1; v2 = nv2; i2 = ni2; v3 = nv3;
            } else {
                if (o1 > v2) { v3 = fmaxf(v2, o2); v2 = o1; i2 = oi1; }
                else         { v3 = fmaxf(v3, o1); }
            }
        }
        if (lane == 0) {
            const int row = row0 + row_l;
            const float margin = fminf(v1 - v2, v2 - v3);
            if (margin < MARGIN_THRESH) {
                const int idx = atomicAdd(flagcnt, 1);
                if (idx < LCAP) flaglist[idx] = row;
            }
            const float e2  = __expf(v2 - v1);
            const float inv = 1.0f / (1.0f + e2);
            *(float2*)&out[row * 2]              = make_float2(inv, e2 * inv);
            *(float2*)&out[2 * BATCHN + row * 2] = make_float2((float)i1, (float)i2);
        }
    }
}

// ---------------- Kernel B: exact f64 recheck of flagged rows (compacted list) ----
__global__ __launch_bounds__(256, 2)
void recheck_kernel(const float* __restrict__ x, const float* __restrict__ W,
                    const float* __restrict__ bias, float* __restrict__ out,
                    const int* __restrict__ flagcnt, const int* __restrict__ flaglist)
{
    __shared__ double sh[NEXP];
    const int tid = threadIdx.x;
    const int e = tid >> 2, q = tid & 3;          // 4 threads/expert, 512-elem K slices
    int cnt = *flagcnt;
    if (cnt > LCAP) cnt = LCAP;

    #pragma unroll 1
    for (int i = blockIdx.x; i < cnt; i += gridDim.x) {
        const int row = flaglist[i];
        const float* xr = x + (size_t)row * EMBED + q * 512;
        const float* wr = W + (size_t)e * EMBED + q * 512;
        double s = 0.0;
        #pragma unroll 4
        for (int k = 0; k < 512; k += 4) {
            const float4 xv = *(const float4*)(xr + k);
            const float4 wv = *(const float4*)(wr + k);
            s += (double)xv.x * (double)wv.x;
            s += (double)xv.y * (double)wv.y;
            s += (double)xv.z * (double)wv.z;
            s += (double)xv.w * (double)wv.w;
        }
        s += __shfl_xor(s, 1, 64);                // reduce 4 K-slices (contiguous lanes)
        s += __shfl_xor(s, 2, 64);
        if (q == 0) sh[e] = s + (double)bias[e];
        __syncthreads();
        if (tid == 0) {
            double v1 = -1e300, v2 = -1e300; int i1 = 0, i2 = 0;
            for (int ee = 0; ee < NEXP; ++ee) {   // ascending: ties keep lower index
                const double v = sh[ee];
                if (v > v1)      { v2 = v1; i2 = i1; v1 = v; i1 = ee; }
                else if (v > v2) { v2 = v; i2 = ee; }
            }
            const double ex  = exp(v2 - v1);
            const double inv = 1.0 / (1.0 + ex);
            out[row * 2]                  = (float)inv;
            out[row * 2 + 1]              = (float)(ex * inv);
            out[2 * BATCHN + row * 2]     = (float)i1;
            out[2 * BATCHN + row * 2 + 1] = (float)i2;
        }
        __syncthreads();
    }
}

extern "C" void kernel_launch(void* const* d_in, const int* in_sizes, int n_in,
                              void* d_out, int out_size, void* d_ws, size_t ws_size,
                              hipStream_t stream) {
    const float* x = (const float*)d_in[0];
    const float* W = (const float*)d_in[1];
    const float* b = (const float*)d_in[2];
    float* out = (float*)d_out;
    // ws layout (576KB):
    //   [0,4)        flag count
    //   [16, 65536)  flag list (LCAP=16380 ints)
    //   [64K, 320K)  Wh  (4 tiles * 64 kcg * 64 lanes * 8 bf16 = 256KB)
    //   [320K, 576K) Wl
    int*    flagcnt  = (int*)d_ws;
    int*    flaglist = flagcnt + 4;
    __bf16* Wh = (__bf16*)((char*)d_ws + 65536);
    __bf16* Wl = (__bf16*)((char*)d_ws + 65536 + 262144);
    pack_w_kernel   <<<dim3(64),          dim3(256),  0, stream>>>(W, Wh, Wl, flagcnt);
    gemm_topk_kernel<<<dim3(BATCHN / RT), dim3(NT_A), 0, stream>>>(x, Wh, Wl, b, out, flagcnt, flaglist);
    recheck_kernel  <<<dim3(128),         dim3(256),  0, stream>>>(x, W, b, out, flagcnt, flaglist);
}

// Round 7
// 243.008 us; speedup vs baseline: 1.0520x; 1.0520x over previous
//
#include <hip/hip_runtime.h>
#include <math.h>

#define EMBED   2048
#define NEXP    64
#define BATCHN  16384
#define RT      32              // rows per block (dual A-fragments per wave)
#define NT_A    256
#define LCAP    16380           // flag-list capacity (fits in 64KB ws slot)
#define MARGIN_THRESH 4e-4f     // bf16-split logit err ~1e-5 abs; 40x margin

typedef float  f32x4  __attribute__((ext_vector_type(4)));
typedef __bf16 bf16x8 __attribute__((ext_vector_type(8)));

// split fp32 -> bf16 hi + bf16 lo (x ~= hi + lo, residual ~2^-18 |x|)
__device__ __forceinline__ void cvt8(const float4& a, const float4& b,
                                     bf16x8& h, bf16x8& l) {
    float f[8] = {a.x, a.y, a.z, a.w, b.x, b.y, b.z, b.w};
    #pragma unroll
    for (int j = 0; j < 8; ++j) {
        __bf16 hh = (__bf16)f[j];
        h[j] = hh;
        l[j] = (__bf16)(f[j] - (float)hh);   // x - hi exact in fp32
    }
}

// ---------------- Kernel 0: pack W -> hi/lo B-fragment layout, zero flag count ----
// Wt[tile][kcg][lane][8]: lane holds col=lane&15, k=kcg*32+(lane>>4)*8+j.
// Same (lane>>4, j) -> k mapping used for the A fragments => K-consistent.
// (hardware-verified rounds 3/5)
__global__ __launch_bounds__(256)
void pack_w_kernel(const float* __restrict__ W, __bf16* __restrict__ Wh,
                   __bf16* __restrict__ Wl, int* __restrict__ flagcnt)
{
    const int g = blockIdx.x * 256 + threadIdx.x;    // 16384 = 4 tiles * 64 kcg * 64 lanes
    if (g == 0) *flagcnt = 0;
    const int tile = g >> 12, rem = g & 4095;
    const int kc = rem >> 6, ln = rem & 63;
    const int e = tile * 16 + (ln & 15);
    const int k = kc * 32 + (ln >> 4) * 8;
    const float* wp = W + (size_t)e * EMBED + k;
    float4 a = *(const float4*)wp, b = *(const float4*)(wp + 4);
    bf16x8 h, l;
    cvt8(a, b, h, l);
    *(bf16x8*)(Wh + (size_t)g * 8) = h;              // coalesced 16B stores
    *(bf16x8*)(Wl + (size_t)g * 8) = l;
}

// ---------------- Kernel A: bf16-split MFMA GEMM + fused top-2 (R5 + deep prefetch) ----
// R5 structure (proven): 32 rows/block, 4 waves = 4 expert tiles, LDS-staged A
// (double-buffered, 1 barrier/stage), 6 MFMA per W-load pair. One change:
// x prefetch deepened to ~2 stages (issue s+1 before the prologue barrier,
// s+2 at the top of stage s) to cover the ~900-cyc HBM latency that the R5
// one-stage distance only marginally covered (FETCH_SIZE shows ~half of x
// misses L3). +32 VGPR, harmless at grid-limited 2 blocks/CU.
__global__ __launch_bounds__(NT_A, 2)
void gemm_topk_kernel(const float* __restrict__ x, const __bf16* __restrict__ Wh,
                      const __bf16* __restrict__ Wl, const float* __restrict__ bias,
                      float* __restrict__ out, int* __restrict__ flagcnt,
                      int* __restrict__ flaglist)
{
    __shared__ __align__(16) __bf16 Ah[2][4096];   // [rh*4+kc][lane][8]
    __shared__ __align__(16) __bf16 Al[2][4096];
    __shared__ float lg[RT][64];

    const int tid  = threadIdx.x;
    const int lane = tid & 63;
    const int w    = tid >> 6;                     // wave = expert tile = staging kc
    const int row0 = blockIdx.x * RT;

    // staging source: rows r0 = row0+(lane&15) (rh=0) and r0+16 (rh=1),
    // k = s*128 + w*32 + (lane>>4)*8
    const float* xr0 = x + (size_t)(row0 + (lane & 15)) * EMBED + w * 32 + (lane >> 4) * 8;
    const float* xr1 = xr0 + (size_t)16 * EMBED;
    const __bf16* whp = Wh + ((size_t)w * 64 * 64 + lane) * 8;   // + kcg*512
    const __bf16* wlp = Wl + ((size_t)w * 64 * 64 + lane) * 8;

    f32x4 acc0 = {0.f, 0.f, 0.f, 0.f};            // rows rh=0
    f32x4 acc1 = {0.f, 0.f, 0.f, 0.f};            // rows rh=1

    {   // prologue: stage 0 direct (both row-halves)
        bf16x8 h, l;
        cvt8(*(const float4*)xr0, *(const float4*)(xr0 + 4), h, l);
        *(bf16x8*)&Ah[0][tid * 8] = h;
        *(bf16x8*)&Al[0][tid * 8] = l;
        cvt8(*(const float4*)xr1, *(const float4*)(xr1 + 4), h, l);
        *(bf16x8*)&Ah[0][2048 + tid * 8] = h;
        *(bf16x8*)&Al[0][2048 + tid * 8] = l;
    }
    // issue stage-1 loads before the barrier (pipeline register set P1)
    float4 p1a0 = *(const float4*)(xr0 + 128), p1b0 = *(const float4*)(xr0 + 132);
    float4 p1a1 = *(const float4*)(xr1 + 128), p1b1 = *(const float4*)(xr1 + 132);
    __syncthreads();

    #pragma unroll 1
    for (int s = 0; s < 16; ++s) {
        const int cur = s & 1;
        float4 p2a0, p2b0, p2a1, p2b1;
        if (s < 14) {                              // issue stage-(s+2) loads (P2)
            p2a0 = *(const float4*)(xr0 + (s + 2) * 128);
            p2b0 = *(const float4*)(xr0 + (s + 2) * 128 + 4);
            p2a1 = *(const float4*)(xr1 + (s + 2) * 128);
            p2b1 = *(const float4*)(xr1 + (s + 2) * 128 + 4);
        }
        #pragma unroll
        for (int kc = 0; kc < 4; ++kc) {
            const int ao = (kc * 64 + lane) * 8;
            bf16x8 ah0 = *(bf16x8*)&Ah[cur][ao];
            bf16x8 al0 = *(bf16x8*)&Al[cur][ao];
            bf16x8 ah1 = *(bf16x8*)&Ah[cur][2048 + ao];
            bf16x8 al1 = *(bf16x8*)&Al[cur][2048 + ao];
            bf16x8 bh  = *(const bf16x8*)(whp + (size_t)(s * 4 + kc) * 512);
            bf16x8 bl  = *(const bf16x8*)(wlp + (size_t)(s * 4 + kc) * 512);
            acc0 = __builtin_amdgcn_mfma_f32_16x16x32_bf16(ah0, bh, acc0, 0, 0, 0);
            acc0 = __builtin_amdgcn_mfma_f32_16x16x32_bf16(ah0, bl, acc0, 0, 0, 0);
            acc0 = __builtin_amdgcn_mfma_f32_16x16x32_bf16(al0, bh, acc0, 0, 0, 0);
            acc1 = __builtin_amdgcn_mfma_f32_16x16x32_bf16(ah1, bh, acc1, 0, 0, 0);
            acc1 = __builtin_amdgcn_mfma_f32_16x16x32_bf16(ah1, bl, acc1, 0, 0, 0);
            acc1 = __builtin_amdgcn_mfma_f32_16x16x32_bf16(al1, bh, acc1, 0, 0, 0);
        }
        if (s < 15) {                              // write stage s+1 from P1
            bf16x8 h, l;
            cvt8(p1a0, p1b0, h, l);
            *(bf16x8*)&Ah[cur ^ 1][tid * 8] = h;
            *(bf16x8*)&Al[cur ^ 1][tid * 8] = l;
            cvt8(p1a1, p1b1, h, l);
            *(bf16x8*)&Ah[cur ^ 1][2048 + tid * 8] = h;
            *(bf16x8*)&Al[cur ^ 1][2048 + tid * 8] = l;
        }
        if (s < 14) { p1a0 = p2a0; p1b0 = p2b0; p1a1 = p2a1; p1b1 = p2b1; }
        __syncthreads();
    }

    // D layout (m89-verified): col = lane&15, row_local = (lane>>4)*4 + reg (+16 for rh=1)
    const float bb = bias[w * 16 + (lane & 15)];
    #pragma unroll
    for (int q = 0; q < 4; ++q) {
        lg[(lane >> 4) * 4 + q][w * 16 + (lane & 15)]      = acc0[q] + bb;
        lg[16 + (lane >> 4) * 4 + q][w * 16 + (lane & 15)] = acc1[q] + bb;
    }
    __syncthreads();

    // top-2 (+margin via top-3): wave w handles rows 8w..8w+7, lane = expert
    #pragma unroll 1
    for (int r = 0; r < 8; ++r) {
        const int row_l = w * 8 + r;
        float v1 = lg[row_l][lane], v2 = -INFINITY, v3 = -INFINITY;
        int   i1 = lane, i2 = 0;
        #pragma unroll
        for (int m = 1; m <= 32; m <<= 1) {
            const float o1  = __shfl_xor(v1, m, 64);
            const int   oi1 = __shfl_xor(i1, m, 64);
            const float o2  = __shfl_xor(v2, m, 64);
            const int   oi2 = __shfl_xor(i2, m, 64);
            const float o3  = __shfl_xor(v3, m, 64);
            if (o1 > v1) {
                float nv2; int ni2; float nv3;
                if (v1 > o2) { nv2 = v1; ni2 = i1;  nv3 = fmaxf(v2, o2); }
                else         { nv2 = o2; ni2 = oi2; nv3 = fmaxf(v1, o3); }
                v1 = o1; i1 = oi1; v2 = nv2; i2 = ni2; v3 = nv3;
            } else {
                if (o1 > v2) { v3 = fmaxf(v2, o2); v2 = o1; i2 = oi1; }
                else         { v3 = fmaxf(v3, o1); }
            }
        }
        if (lane == 0) {
            const int row = row0 + row_l;
            const float margin = fminf(v1 - v2, v2 - v3);
            if (margin < MARGIN_THRESH) {
                const int idx = atomicAdd(flagcnt, 1);
                if (idx < LCAP) flaglist[idx] = row;
            }
            const float e2  = __expf(v2 - v1);
            const float inv = 1.0f / (1.0f + e2);
            *(float2*)&out[row * 2]              = make_float2(inv, e2 * inv);
            *(float2*)&out[2 * BATCHN + row * 2] = make_float2((float)i1, (float)i2);
        }
    }
}

// ---------------- Kernel B: exact f64 recheck of flagged rows (compacted list) ----
__global__ __launch_bounds__(256, 2)
void recheck_kernel(const float* __restrict__ x, const float* __restrict__ W,
                    const float* __restrict__ bias, float* __restrict__ out,
                    const int* __restrict__ flagcnt, const int* __restrict__ flaglist)
{
    __shared__ double sh[NEXP];
    const int tid = threadIdx.x;
    const int e = tid >> 2, q = tid & 3;          // 4 threads/expert, 512-elem K slices
    int cnt = *flagcnt;
    if (cnt > LCAP) cnt = LCAP;

    #pragma unroll 1
    for (int i = blockIdx.x; i < cnt; i += gridDim.x) {
        const int row = flaglist[i];
        const float* xr = x + (size_t)row * EMBED + q * 512;
        const float* wr = W + (size_t)e * EMBED + q * 512;
        double s = 0.0;
        #pragma unroll 4
        for (int k = 0; k < 512; k += 4) {
            const float4 xv = *(const float4*)(xr + k);
            const float4 wv = *(const float4*)(wr + k);
            s += (double)xv.x * (double)wv.x;
            s += (double)xv.y * (double)wv.y;
            s += (double)xv.z * (double)wv.z;
            s += (double)xv.w * (double)wv.w;
        }
        s += __shfl_xor(s, 1, 64);                // reduce 4 K-slices (contiguous lanes)
        s += __shfl_xor(s, 2, 64);
        if (q == 0) sh[e] = s + (double)bias[e];
        __syncthreads();
        if (tid == 0) {
            double v1 = -1e300, v2 = -1e300; int i1 = 0, i2 = 0;
            for (int ee = 0; ee < NEXP; ++ee) {   // ascending: ties keep lower index
                const double v = sh[ee];
                if (v > v1)      { v2 = v1; i2 = i1; v1 = v; i1 = ee; }
                else if (v > v2) { v2 = v; i2 = ee; }
            }
            const double ex  = exp(v2 - v1);
            const double inv = 1.0 / (1.0 + ex);
            out[row * 2]                  = (float)inv;
            out[row * 2 + 1]              = (float)(ex * inv);
            out[2 * BATCHN + row * 2]     = (float)i1;
            out[2 * BATCHN + row * 2 + 1] = (float)i2;
        }
        __syncthreads();
    }
}

extern "C" void kernel_launch(void* const* d_in, const int* in_sizes, int n_in,
                              void* d_out, int out_size, void* d_ws, size_t ws_size,
                              hipStream_t stream) {
    const float* x = (const float*)d_in[0];
    const float* W = (const float*)d_in[1];
    const float* b = (const float*)d_in[2];
    float* out = (float*)d_out;
    // ws layout (576KB):
    //   [0,4)        flag count
    //   [16, 65536)  flag list (LCAP=16380 ints)
    //   [64K, 320K)  Wh  (4 tiles * 64 kcg * 64 lanes * 8 bf16 = 256KB)
    //   [320K, 576K) Wl
    int*    flagcnt  = (int*)d_ws;
    int*    flaglist = flagcnt + 4;
    __bf16* Wh = (__bf16*)((char*)d_ws + 65536);
    __bf16* Wl = (__bf16*)((char*)d_ws + 65536 + 262144);
    pack_w_kernel   <<<dim3(64),          dim3(256),  0, stream>>>(W, Wh, Wl, flagcnt);
    gemm_topk_kernel<<<dim3(BATCHN / RT), dim3(NT_A), 0, stream>>>(x, Wh, Wl, b, out, flagcnt, flaglist);
    recheck_kernel  <<<dim3(128),         dim3(256),  0, stream>>>(x, W, b, out, flagcnt, flaglist);
}

// Round 8
// 240.776 us; speedup vs baseline: 1.0618x; 1.0093x over previous
//
#include <hip/hip_runtime.h>
#include <math.h>

#define EMBED   2048
#define NEXP    64
#define BATCHN  16384
#define RT      32              // rows per block
#define NT_A    256
#define LCAP    16380           // flag-list capacity (fits in 64KB ws slot)
#define MARGIN_THRESH 4e-4f     // bf16-split logit err ~1e-5 abs; 40x margin

typedef float  f32x4  __attribute__((ext_vector_type(4)));
typedef __bf16 bf16x8 __attribute__((ext_vector_type(8)));

// split fp32 -> bf16 hi + bf16 lo (x ~= hi + lo, residual ~2^-18 |x|)
__device__ __forceinline__ void cvt8(const float4& a, const float4& b,
                                     bf16x8& h, bf16x8& l) {
    float f[8] = {a.x, a.y, a.z, a.w, b.x, b.y, b.z, b.w};
    #pragma unroll
    for (int j = 0; j < 8; ++j) {
        __bf16 hh = (__bf16)f[j];
        h[j] = hh;
        l[j] = (__bf16)(f[j] - (float)hh);   // x - hi exact in fp32
    }
}

// async 16B global->LDS copy (dest = wave-uniform base + lane*16, src per-lane)
__device__ __forceinline__ void gload_lds16(const float* g, float* lds) {
    __builtin_amdgcn_global_load_lds(
        (const __attribute__((address_space(1))) unsigned int*)g,
        (__attribute__((address_space(3))) unsigned int*)lds,
        16, 0, 0);
}

// ---------------- Kernel 0: pack W -> hi/lo B-fragment layout, zero flag count ----
// Wt[tile][kcg][lane][8]: lane holds col=lane&15, k=kcg*32+(lane>>4)*8+j.
// Same (lane>>4, j) -> k mapping used for the A fragments => K-consistent.
// (hardware-verified rounds 3/5/7)
__global__ __launch_bounds__(256)
void pack_w_kernel(const float* __restrict__ W, __bf16* __restrict__ Wh,
                   __bf16* __restrict__ Wl, int* __restrict__ flagcnt)
{
    const int g = blockIdx.x * 256 + threadIdx.x;    // 16384 = 4 tiles * 64 kcg * 64 lanes
    if (g == 0) *flagcnt = 0;
    const int tile = g >> 12, rem = g & 4095;
    const int kc = rem >> 6, ln = rem & 63;
    const int e = tile * 16 + (ln & 15);
    const int k = kc * 32 + (ln >> 4) * 8;
    const float* wp = W + (size_t)e * EMBED + k;
    float4 a = *(const float4*)wp, b = *(const float4*)(wp + 4);
    bf16x8 h, l;
    cvt8(a, b, h, l);
    *(bf16x8*)(Wh + (size_t)g * 8) = h;              // coalesced 16B stores
    *(bf16x8*)(Wl + (size_t)g * 8) = l;
}

// ---------------- Kernel A: async-staged bf16-split MFMA GEMM + fused top-2 ----
// R5 schedule (32 rows/block, 4 waves = 4 expert tiles, dbuf LDS, 1 barrier/stage,
// 6 MFMA per W-load pair) with the staging path replaced by global_load_lds:
//  - raw fp32 x staged async to LDS (no VGPR round-trip, no producer cvt,
//    coalesced 512B row segments), barrier's vmcnt(0) drain is the only wait;
//  - 16B-unit XOR swizzle (unit ^= row&7) applied on the SOURCE address
//    (gload_lds dest must be linear) => conflict-free fragment ds_read_b128;
//  - consumers cvt8 fp32->bf16 hi/lo on read (hidden under x delivery).
__global__ __launch_bounds__(NT_A, 2)
void gemm_topk_kernel(const float* __restrict__ x, const __bf16* __restrict__ Wh,
                      const __bf16* __restrict__ Wl, const float* __restrict__ bias,
                      float* __restrict__ out, int* __restrict__ flagcnt,
                      int* __restrict__ flaglist)
{
    __shared__ __align__(16) float Xs[2][RT * 128];  // raw fp32 stage, 2 x 16 KB
    __shared__ float lg[RT][64];                     // 8 KB

    const int tid  = threadIdx.x;
    const int lane = tid & 63;
    const int w    = tid >> 6;                     // wave = expert tile
    const int row0 = blockIdx.x * RT;

    // staging: wave w fills 16B-units [w*256, (w+1)*256) of the 1024-unit stage.
    // dest unit d = (w*4+i)*64 + lane -> row = d>>5, in-row unit v = d&31.
    // source carries the inverse swizzle: cu = v ^ (row&7)  (involution).
    const float* gsrc[4];
    #pragma unroll
    for (int i = 0; i < 4; ++i) {
        const int d   = (w * 4 + i) * 64 + lane;
        const int row = d >> 5;
        const int cu  = (d & 31) ^ (row & 7);
        gsrc[i] = x + (size_t)(row0 + row) * EMBED + cu * 4;
    }

    const __bf16* whp = Wh + ((size_t)w * 64 * 64 + lane) * 8;   // + kcg*512
    const __bf16* wlp = Wl + ((size_t)w * 64 * 64 + lane) * 8;

    f32x4 acc0 = {0.f, 0.f, 0.f, 0.f};            // rows rh=0
    f32x4 acc1 = {0.f, 0.f, 0.f, 0.f};            // rows rh=1

    // prologue: stage 0 async, drained by the barrier below
    #pragma unroll
    for (int i = 0; i < 4; ++i)
        gload_lds16(gsrc[i], &Xs[0][(w * 4 + i) * 256]);
    __syncthreads();

    const int r0i = lane & 15;                     // fragment rows (rh=0 / rh=1)
    const int r1i = r0i + 16;
    const int sw  = r0i & 7;                       // swizzle key (same for r1i)

    #pragma unroll 1
    for (int s = 0; s < 16; ++s) {
        const int cur = s & 1;
        if (s < 15) {                              // async-stage s+1 into the other buffer
            #pragma unroll
            for (int i = 0; i < 4; ++i)
                gload_lds16(gsrc[i] + (s + 1) * 128, &Xs[cur ^ 1][(w * 4 + i) * 256]);
        }
        const float* xs = &Xs[cur][0];
        #pragma unroll
        for (int kc = 0; kc < 4; ++kc) {
            const int cb = kc * 8 + ((lane >> 4) & 3) * 2;   // even 16B-unit index
            float4 a0 = *(const float4*)&xs[r0i * 128 + ((cb    ) ^ sw) * 4];
            float4 b0 = *(const float4*)&xs[r0i * 128 + ((cb + 1) ^ sw) * 4];
            float4 a1 = *(const float4*)&xs[r1i * 128 + ((cb    ) ^ sw) * 4];
            float4 b1 = *(const float4*)&xs[r1i * 128 + ((cb + 1) ^ sw) * 4];
            bf16x8 ah0, al0, ah1, al1;
            cvt8(a0, b0, ah0, al0);
            cvt8(a1, b1, ah1, al1);
            bf16x8 bh = *(const bf16x8*)(whp + (size_t)(s * 4 + kc) * 512);
            bf16x8 bl = *(const bf16x8*)(wlp + (size_t)(s * 4 + kc) * 512);
            acc0 = __builtin_amdgcn_mfma_f32_16x16x32_bf16(ah0, bh, acc0, 0, 0, 0);
            acc0 = __builtin_amdgcn_mfma_f32_16x16x32_bf16(ah0, bl, acc0, 0, 0, 0);
            acc0 = __builtin_amdgcn_mfma_f32_16x16x32_bf16(al0, bh, acc0, 0, 0, 0);
            acc1 = __builtin_amdgcn_mfma_f32_16x16x32_bf16(ah1, bh, acc1, 0, 0, 0);
            acc1 = __builtin_amdgcn_mfma_f32_16x16x32_bf16(ah1, bl, acc1, 0, 0, 0);
            acc1 = __builtin_amdgcn_mfma_f32_16x16x32_bf16(al1, bh, acc1, 0, 0, 0);
        }
        __syncthreads();                           // drains vmcnt -> stage s+1 ready
    }

    // D layout (m89-verified): col = lane&15, row_local = (lane>>4)*4 + reg (+16 for rh=1)
    const float bb = bias[w * 16 + (lane & 15)];
    #pragma unroll
    for (int q = 0; q < 4; ++q) {
        lg[(lane >> 4) * 4 + q][w * 16 + (lane & 15)]      = acc0[q] + bb;
        lg[16 + (lane >> 4) * 4 + q][w * 16 + (lane & 15)] = acc1[q] + bb;
    }
    __syncthreads();

    // top-2 (+margin via top-3): wave w handles rows 8w..8w+7, lane = expert
    #pragma unroll 1
    for (int r = 0; r < 8; ++r) {
        const int row_l = w * 8 + r;
        float v1 = lg[row_l][lane], v2 = -INFINITY, v3 = -INFINITY;
        int   i1 = lane, i2 = 0;
        #pragma unroll
        for (int m = 1; m <= 32; m <<= 1) {
            const float o1  = __shfl_xor(v1, m, 64);
            const int   oi1 = __shfl_xor(i1, m, 64);
            const float o2  = __shfl_xor(v2, m, 64);
            const int   oi2 = __shfl_xor(i2, m, 64);
            const float o3  = __shfl_xor(v3, m, 64);
            if (o1 > v1) {
                float nv2; int ni2; float nv3;
                if (v1 > o2) { nv2 = v1; ni2 = i1;  nv3 = fmaxf(v2, o2); }
                else         { nv2 = o2; ni2 = oi2; nv3 = fmaxf(v1, o3); }
                v1 = o1; i1 = oi1; v2 = nv2; i2 = ni2; v3 = nv3;
            } else {
                if (o1 > v2) { v3 = fmaxf(v2, o2); v2 = o1; i2 = oi1; }
                else         { v3 = fmaxf(v3, o1); }
            }
        }
        if (lane == 0) {
            const int row = row0 + row_l;
            const float margin = fminf(v1 - v2, v2 - v3);
            if (margin < MARGIN_THRESH) {
                const int idx = atomicAdd(flagcnt, 1);
                if (idx < LCAP) flaglist[idx] = row;
            }
            const float e2  = __expf(v2 - v1);
            const float inv = 1.0f / (1.0f + e2);
            *(float2*)&out[row * 2]              = make_float2(inv, e2 * inv);
            *(float2*)&out[2 * BATCHN + row * 2] = make_float2((float)i1, (float)i2);
        }
    }
}

// ---------------- Kernel B: exact f64 recheck of flagged rows (compacted list) ----
__global__ __launch_bounds__(256, 2)
void recheck_kernel(const float* __restrict__ x, const float* __restrict__ W,
                    const float* __restrict__ bias, float* __restrict__ out,
                    const int* __restrict__ flagcnt, const int* __restrict__ flaglist)
{
    __shared__ double sh[NEXP];
    const int tid = threadIdx.x;
    const int e = tid >> 2, q = tid & 3;          // 4 threads/expert, 512-elem K slices
    int cnt = *flagcnt;
    if (cnt > LCAP) cnt = LCAP;

    #pragma unroll 1
    for (int i = blockIdx.x; i < cnt; i += gridDim.x) {
        const int row = flaglist[i];
        const float* xr = x + (size_t)row * EMBED + q * 512;
        const float* wr = W + (size_t)e * EMBED + q * 512;
        double s = 0.0;
        #pragma unroll 4
        for (int k = 0; k < 512; k += 4) {
            const float4 xv = *(const float4*)(xr + k);
            const float4 wv = *(const float4*)(wr + k);
            s += (double)xv.x * (double)wv.x;
            s += (double)xv.y * (double)wv.y;
            s += (double)xv.z * (double)wv.z;
            s += (double)xv.w * (double)wv.w;
        }
        s += __shfl_xor(s, 1, 64);                // reduce 4 K-slices (contiguous lanes)
        s += __shfl_xor(s, 2, 64);
        if (q == 0) sh[e] = s + (double)bias[e];
        __syncthreads();
        if (tid == 0) {
            double v1 = -1e300, v2 = -1e300; int i1 = 0, i2 = 0;
            for (int ee = 0; ee < NEXP; ++ee) {   // ascending: ties keep lower index
                const double v = sh[ee];
                if (v > v1)      { v2 = v1; i2 = i1; v1 = v; i1 = ee; }
                else if (v > v2) { v2 = v; i2 = ee; }
            }
            const double ex  = exp(v2 - v1);
            const double inv = 1.0 / (1.0 + ex);
            out[row * 2]                  = (float)inv;
            out[row * 2 + 1]              = (float)(ex * inv);
            out[2 * BATCHN + row * 2]     = (float)i1;
            out[2 * BATCHN + row * 2 + 1] = (float)i2;
        }
        __syncthreads();
    }
}

extern "C" void kernel_launch(void* const* d_in, const int* in_sizes, int n_in,
                              void* d_out, int out_size, void* d_ws, size_t ws_size,
                              hipStream_t stream) {
    const float* x = (const float*)d_in[0];
    const float* W = (const float*)d_in[1];
    const float* b = (const float*)d_in[2];
    float* out = (float*)d_out;
    // ws layout (576KB):
    //   [0,4)        flag count
    //   [16, 65536)  flag list (LCAP=16380 ints)
    //   [64K, 320K)  Wh  (4 tiles * 64 kcg * 64 lanes * 8 bf16 = 256KB)
    //   [320K, 576K) Wl
    int*    flagcnt  = (int*)d_ws;
    int*    flaglist = flagcnt + 4;
    __bf16* Wh = (__bf16*)((char*)d_ws + 65536);
    __bf16* Wl = (__bf16*)((char*)d_ws + 65536 + 262144);
    pack_w_kernel   <<<dim3(64),          dim3(256),  0, stream>>>(W, Wh, Wl, flagcnt);
    gemm_topk_kernel<<<dim3(BATCHN / RT), dim3(NT_A), 0, stream>>>(x, Wh, Wl, b, out, flagcnt, flaglist);
    recheck_kernel  <<<dim3(128),         dim3(256),  0, stream>>>(x, W, b, out, flagcnt, flaglist);
}